// Round 5
// baseline (371.750 us; speedup 1.0000x reference)
//
#include <hip/hip_runtime.h>
#include <cstddef>
#include <cstdint>

#define NTOK 4096
#define NB_  8

typedef float f32x4  __attribute__((ext_vector_type(4)));
typedef float f32x16 __attribute__((ext_vector_type(16)));
typedef short s16x8  __attribute__((ext_vector_type(8)));

static __device__ __forceinline__ unsigned short f2bf(float f) {
    unsigned u = __float_as_uint(f);
    unsigned r = (u + 0x7FFFu + ((u >> 16) & 1u)) >> 16;
    return (unsigned short)r;
}
static __device__ __forceinline__ unsigned packbf2(float a, float b) {
    const unsigned ua = __float_as_uint(a) + 0x8000u;
    const unsigned ub = __float_as_uint(b) + 0x8000u;
    return __builtin_amdgcn_perm(ub, ua, 0x07060302u);  // [bf16(a), bf16(b)]
}

// ---------------- P0: weights fp32 -> bf16 ----------------
__global__ __launch_bounds__(256) void wcvt_kernel(
    const float* __restrict__ Wq, const float* __restrict__ Wk, const float* __restrict__ Wv,
    unsigned short* __restrict__ wvb, unsigned short* __restrict__ wqb,
    unsigned short* __restrict__ wkb)
{
    int i = blockIdx.x * 256 + threadIdx.x;  // 0..20479
    if (i < 16384)      wvb[i]         = f2bf(Wv[i]);
    else if (i < 18432) wqb[i - 16384] = f2bf(Wq[i - 16384]);
    else                wkb[i - 18432] = f2bf(Wk[i - 18432]);
}

// ---------------- P1: fused transpose + projections ----------------
// Flat grid 512 blocks; b = blk & 7 pins each batch to one XCD so outputs land
// in the L2 flash will read. V is written in flash's fragment-major layout:
// v3[b][jt=j>>6][s=(j>>4)&3][h=(j>>3)&1][c][e=j&7]
__global__ __launch_bounds__(256) void proj_kernel(
    const float* __restrict__ x,
    const unsigned short* __restrict__ wvb, const unsigned short* __restrict__ wqb,
    const unsigned short* __restrict__ wkb,
    const float* __restrict__ bq, const float* __restrict__ bk, const float* __restrict__ bv,
    unsigned short* __restrict__ qb, unsigned short* __restrict__ kb,
    unsigned short* __restrict__ vt)
{
    __shared__ float lt[128][68];   // [c][n0..63], padded rows
    const int t = threadIdx.x;
    const int w = t >> 6, lane = t & 63;
    const int c16 = lane & 15, g16 = lane >> 4;
    const int b  = blockIdx.x & 7;
    const int n0 = (blockIdx.x >> 3) * 64;

    // stage x tile: 128 rows x 64 floats
    {
        const int n4 = t & 15;
#pragma unroll
        for (int pass = 0; pass < 8; ++pass) {
            const int c = (t >> 4) + 16 * pass;
            const float4 val = ((const float4*)(x + ((size_t)b * 128 + c) * NTOK + n0))[n4];
            *(float4*)&lt[c][n4 * 4] = val;
        }
    }
    __syncthreads();

    // xf fragments for this wave's 16 tokens (token = n0 + 16w + c16)
    const int nl = 16 * w + c16;
    s16x8 xf[4];
#pragma unroll
    for (int kc = 0; kc < 4; ++kc) {
        unsigned rr[8];
#pragma unroll
        for (int i = 0; i < 8; ++i) {
            const unsigned u = __float_as_uint(lt[32 * kc + 8 * g16 + i][nl]);
            rr[i] = u + 0x7FFFu + ((u >> 16) & 1u);
        }
        union { s16x8 v; unsigned u[4]; } cvt;
#pragma unroll
        for (int d = 0; d < 4; ++d)
            cvt.u[d] = __builtin_amdgcn_perm(rr[2 * d + 1], rr[2 * d], 0x07060302u);
        xf[kc] = cvt.v;
    }

    // ---- V = Wv * X  (stored fragment-major for flash) ----
    // token j = n0 + 16w + c16: jt = n0>>6, s = w, h = c16>>3, e = c16&7
    unsigned short* vwp = vt + (size_t)b * (NTOK * 128) +
                          (size_t)(((n0 >> 6) * 8) + 2 * w + (c16 >> 3)) * 1024 + (c16 & 7);
#pragma unroll
    for (int mt = 0; mt < 8; ++mt) {
        f32x4 acc = {0.f, 0.f, 0.f, 0.f};
#pragma unroll
        for (int kc = 0; kc < 4; ++kc) {
            const s16x8 wf = *(const s16x8*)(wvb + (size_t)(16 * mt + c16) * 128 + 32 * kc + 8 * g16);
            acc = __builtin_amdgcn_mfma_f32_16x16x32_bf16(wf, xf[kc], acc, 0, 0, 0);
        }
        const float4 bvv = *(const float4*)(bv + 16 * mt + 4 * g16);
#pragma unroll
        for (int r = 0; r < 4; ++r) {
            const int c = 16 * mt + 4 * g16 + r;
            vwp[c * 8] = f2bf(acc[r] + ((const float*)&bvv)[r]);
        }
    }
    // ---- Q, K ----
    f32x4 aq = {0.f, 0.f, 0.f, 0.f}, ak = {0.f, 0.f, 0.f, 0.f};
#pragma unroll
    for (int kc = 0; kc < 4; ++kc) {
        const s16x8 wqf = *(const s16x8*)(wqb + (size_t)c16 * 128 + 32 * kc + 8 * g16);
        const s16x8 wkf = *(const s16x8*)(wkb + (size_t)c16 * 128 + 32 * kc + 8 * g16);
        aq = __builtin_amdgcn_mfma_f32_16x16x32_bf16(xf[kc], wqf, aq, 0, 0, 0);
        ak = __builtin_amdgcn_mfma_f32_16x16x32_bf16(xf[kc], wkf, ak, 0, 0, 0);
    }
    const float bqv = bq[c16], bkv = bk[c16];
#pragma unroll
    for (int r = 0; r < 4; ++r) {
        const int n = n0 + 16 * w + 4 * g16 + r;
        qb[((size_t)b * NTOK + n) * 16 + c16] = f2bf(0.25f * (aq[r] + bqv));
        kb[((size_t)b * NTOK + n) * 16 + c16] = f2bf(ak[r] + bkv);
    }
}

// ---------------- P2: flash attention, 32x32x16 MFMA, XCD-pinned ----------------
// Flat grid 1024 blocks: b = blk & 7 (one batch per XCD), m-tile = blk >> 3 (32 q rows).
// 4 waves: wave w covers j in [w*1024, (w+1)*1024); partials combined via LDS.
// launch_bounds (256,4): 4 waves/EU -> 4 blocks/CU resident (whole grid one pass).
__global__ __launch_bounds__(256, 4) void flash_kernel(
    const unsigned short* __restrict__ qb, const unsigned short* __restrict__ kb,
    const unsigned short* __restrict__ vt, const float* __restrict__ x,
    const float* __restrict__ gamma, float* __restrict__ out)
{
    __shared__ unsigned smem[4608];  // loop: pw[4][1024]; end: ob[128*33] + lb[32]

    const int t = threadIdx.x;
    const int w = t >> 6, lane = t & 63;
    const int m31 = lane & 31, h = lane >> 5;
    const int b  = blockIdx.x & 7;
    const int m0 = (blockIdx.x >> 3) * 32;

    unsigned* pwm = smem + w * 1024;

    const unsigned short* kbb = kb + ((size_t)b * NTOK + w * 1024) * 16;
    // fragment-major V base for this wave's 16 jt tiles
    const unsigned short* vtb = vt + (size_t)b * (NTOK * 128) + (size_t)w * 16 * 8192 +
                                h * 1024 + m31 * 8;

    // Q B-frag: B[k=ch 8h+e][n=m31]; scale pre-folded into qb.
    const s16x8 qf = *(const s16x8*)(qb + ((size_t)b * NTOK + m0 + m31) * 16 + 8 * h);

    f32x16 O[4];
#pragma unroll
    for (int ct = 0; ct < 4; ++ct)
#pragma unroll
        for (int r = 0; r < 16; ++r) O[ct][r] = 0.f;
    float l_acc = 0.f;

    // K A-frags for jt=0
    s16x8 kf0 = *(const s16x8*)(kbb + (size_t)m31 * 16 + 8 * h);
    s16x8 kf1 = *(const s16x8*)(kbb + (size_t)(32 + m31) * 16 + 8 * h);

    for (int jt = 0; jt < 16; ++jt) {
        const int j0 = jt * 64;

        // V A-frags, fully coalesced: vf[ct][s] = V^T[c=32ct+m31][j0+16s+8h+e]
        s16x8 vf[4][4];
#pragma unroll
        for (int s = 0; s < 4; ++s)
#pragma unroll
            for (int ct = 0; ct < 4; ++ct)
                vf[ct][s] = *(const s16x8*)(vtb + jt * 8192 + s * 2048 + ct * 256);

        // scores: S^T tiles (D[j][m])
        f32x16 sd[2];
#pragma unroll
        for (int r = 0; r < 16; ++r) { sd[0][r] = 0.f; sd[1][r] = 0.f; }
        sd[0] = __builtin_amdgcn_mfma_f32_32x32x16_bf16(kf0, qf, sd[0], 0, 0, 0);
        sd[1] = __builtin_amdgcn_mfma_f32_32x32x16_bf16(kf1, qf, sd[1], 0, 0, 0);

        // prefetch next K frags
        if (jt < 15) {
            kf0 = *(const s16x8*)(kbb + (size_t)(j0 + 64 + m31) * 16 + 8 * h);
            kf1 = *(const s16x8*)(kbb + (size_t)(j0 + 96 + m31) * 16 + 8 * h);
        }

        // softmax without max-subtraction (|s| bounded; exp safe in fp32)
#pragma unroll
        for (int t2 = 0; t2 < 2; ++t2)
#pragma unroll
            for (int r = 0; r < 16; ++r) {
                const float e = __expf(sd[t2][r]);
                sd[t2][r] = e;
                l_acc += e;
            }

        // scatter P into B-frag order:
        // value (t2,q,r4,h) -> frag s=2*t2+(q>>1), lane (q&1)*32+m31, elem 4h+r4
        __builtin_amdgcn_wave_barrier();
#pragma unroll
        for (int t2 = 0; t2 < 2; ++t2)
#pragma unroll
            for (int q = 0; q < 4; ++q) {
                const unsigned d0 = packbf2(sd[t2][4 * q + 0], sd[t2][4 * q + 1]);
                const unsigned d1 = packbf2(sd[t2][4 * q + 2], sd[t2][4 * q + 3]);
                const int addr = (2 * t2 + (q >> 1)) * 256 + ((q & 1) * 32 + m31) * 4 + 2 * h;
                *(uint2*)&pwm[addr] = (uint2){d0, d1};
            }
        __builtin_amdgcn_wave_barrier();

        s16x8 pf[4];
#pragma unroll
        for (int s = 0; s < 4; ++s)
            pf[s] = *(const s16x8*)(pwm + s * 256 + lane * 4);

        // PV: O^T[c][m] += V^T * P^T
#pragma unroll
        for (int s = 0; s < 4; ++s)
#pragma unroll
            for (int ct = 0; ct < 4; ++ct)
                O[ct] = __builtin_amdgcn_mfma_f32_32x32x16_bf16(vf[ct][s], pf[s], O[ct], 0, 0, 0);
    }

    // finish this wave's l (two h-halves hold disjoint j subsets)
    l_acc += __shfl_xor(l_acc, 32);

    // ---- combine 4 j-partials via LDS (sequential, reuses pw space) ----
    float* ob = (float*)smem;           // [c][m] stride 33
    float* lb = (float*)smem + 4224;    // [32]
#pragma unroll 1
    for (int src = 1; src < 4; ++src) {
        __syncthreads();
        if (w == src) {
#pragma unroll
            for (int ct = 0; ct < 4; ++ct)
#pragma unroll
                for (int r = 0; r < 16; ++r) {
                    const int c = 32 * ct + (r & 3) + 8 * (r >> 2) + 4 * h;
                    ob[c * 33 + m31] = O[ct][r];
                }
            if (lane < 32) lb[lane] = l_acc;
        }
        __syncthreads();
        if (w == 0) {
#pragma unroll
            for (int ct = 0; ct < 4; ++ct)
#pragma unroll
                for (int r = 0; r < 16; ++r) {
                    const int c = 32 * ct + (r & 3) + 8 * (r >> 2) + 4 * h;
                    O[ct][r] += ob[c * 33 + m31];
                }
            l_acc += lb[m31];
        }
    }

    if (w == 0) {
        const float linv = 1.f / l_acc;
        const float g = gamma[0];
#pragma unroll
        for (int ct = 0; ct < 4; ++ct)
#pragma unroll
            for (int r = 0; r < 16; ++r) {
                const int c = 32 * ct + (r & 3) + 8 * (r >> 2) + 4 * h;
                const size_t idx = ((size_t)b * 128 + c) * NTOK + m0 + m31;
                out[idx] = fmaf(g, O[ct][r] * linv, x[idx]);
            }
    }
}

extern "C" void kernel_launch(void* const* d_in, const int* in_sizes, int n_in,
                              void* d_out, int out_size, void* d_ws, size_t ws_size,
                              hipStream_t stream)
{
    const float* x     = (const float*)d_in[0];
    const float* Wq    = (const float*)d_in[1];
    const float* bq    = (const float*)d_in[2];
    const float* Wk    = (const float*)d_in[3];
    const float* bk    = (const float*)d_in[4];
    const float* Wv    = (const float*)d_in[5];
    const float* bv    = (const float*)d_in[6];
    const float* gamma = (const float*)d_in[7];
    float* out = (float*)d_out;

    // workspace (bf16 elements)
    unsigned short* qb  = (unsigned short*)d_ws;                 // 8*4096*16
    unsigned short* kb  = qb  + (size_t)NB_ * NTOK * 16;
    unsigned short* vt  = kb  + (size_t)NB_ * NTOK * 16;         // 8*128*4096 (fragment-major)
    unsigned short* wvb = vt  + (size_t)NB_ * 128 * NTOK;        // 128*128
    unsigned short* wqb = wvb + 16384;                           // 16*128
    unsigned short* wkb = wqb + 2048;

    wcvt_kernel<<<80, 256, 0, stream>>>(Wq, Wk, Wv, wvb, wqb, wkb);
    proj_kernel<<<512, 256, 0, stream>>>(x, wvb, wqb, wkb, bq, bk, bv, qb, kb, vt);
    flash_kernel<<<1024, 256, 0, stream>>>(qb, kb, vt, x, gamma, out);
}

// Round 7
// 208.851 us; speedup vs baseline: 1.7800x; 1.7800x over previous
//
#include <hip/hip_runtime.h>
#include <cstddef>
#include <cstdint>

#define NTOK 4096
#define NB_  8

typedef float f32x4  __attribute__((ext_vector_type(4)));
typedef float f32x16 __attribute__((ext_vector_type(16)));
typedef short s16x8  __attribute__((ext_vector_type(8)));

static __device__ __forceinline__ unsigned short f2bf(float f) {
    unsigned u = __float_as_uint(f);
    unsigned r = (u + 0x7FFFu + ((u >> 16) & 1u)) >> 16;
    return (unsigned short)r;
}
static __device__ __forceinline__ unsigned packbf2(float a, float b) {
    const unsigned ua = __float_as_uint(a) + 0x8000u;
    const unsigned ub = __float_as_uint(b) + 0x8000u;
    return __builtin_amdgcn_perm(ub, ua, 0x07060302u);  // [bf16(a), bf16(b)]
}

// ---------------- P0: weights fp32 -> bf16 ----------------
__global__ __launch_bounds__(256) void wcvt_kernel(
    const float* __restrict__ Wq, const float* __restrict__ Wk, const float* __restrict__ Wv,
    unsigned short* __restrict__ wvb, unsigned short* __restrict__ wqb,
    unsigned short* __restrict__ wkb)
{
    int i = blockIdx.x * 256 + threadIdx.x;  // 0..20479
    if (i < 16384)      wvb[i]         = f2bf(Wv[i]);
    else if (i < 18432) wqb[i - 16384] = f2bf(Wq[i - 16384]);
    else                wkb[i - 18432] = f2bf(Wk[i - 18432]);
}

// ---------------- P1: fused transpose + projections ----------------
// Flat grid 512 blocks; b = blk & 7 pins each batch to one XCD so outputs land
// in the L2 flash will read. V is written in flash's fragment-major layout:
// v3[b][jt=j>>6][s=(j>>4)&3][h=(j>>3)&1][c][e=j&7]
__global__ __launch_bounds__(256) void proj_kernel(
    const float* __restrict__ x,
    const unsigned short* __restrict__ wvb, const unsigned short* __restrict__ wqb,
    const unsigned short* __restrict__ wkb,
    const float* __restrict__ bq, const float* __restrict__ bk, const float* __restrict__ bv,
    unsigned short* __restrict__ qb, unsigned short* __restrict__ kb,
    unsigned short* __restrict__ vt)
{
    __shared__ float lt[128][68];   // [c][n0..63], padded rows
    const int t = threadIdx.x;
    const int w = t >> 6, lane = t & 63;
    const int c16 = lane & 15, g16 = lane >> 4;
    const int b  = blockIdx.x & 7;
    const int n0 = (blockIdx.x >> 3) * 64;

    // stage x tile: 128 rows x 64 floats
    {
        const int n4 = t & 15;
#pragma unroll
        for (int pass = 0; pass < 8; ++pass) {
            const int c = (t >> 4) + 16 * pass;
            const float4 val = ((const float4*)(x + ((size_t)b * 128 + c) * NTOK + n0))[n4];
            *(float4*)&lt[c][n4 * 4] = val;
        }
    }
    __syncthreads();

    // xf fragments for this wave's 16 tokens (token = n0 + 16w + c16)
    const int nl = 16 * w + c16;
    s16x8 xf[4];
#pragma unroll
    for (int kc = 0; kc < 4; ++kc) {
        unsigned rr[8];
#pragma unroll
        for (int i = 0; i < 8; ++i) {
            const unsigned u = __float_as_uint(lt[32 * kc + 8 * g16 + i][nl]);
            rr[i] = u + 0x7FFFu + ((u >> 16) & 1u);
        }
        union { s16x8 v; unsigned u[4]; } cvt;
#pragma unroll
        for (int d = 0; d < 4; ++d)
            cvt.u[d] = __builtin_amdgcn_perm(rr[2 * d + 1], rr[2 * d], 0x07060302u);
        xf[kc] = cvt.v;
    }

    // ---- V = Wv * X  (stored fragment-major for flash) ----
    // token j = n0 + 16w + c16: jt = n0>>6, s = w, h = c16>>3, e = c16&7
    unsigned short* vwp = vt + (size_t)b * (NTOK * 128) +
                          (size_t)(((n0 >> 6) * 8) + 2 * w + (c16 >> 3)) * 1024 + (c16 & 7);
#pragma unroll
    for (int mt = 0; mt < 8; ++mt) {
        f32x4 acc = {0.f, 0.f, 0.f, 0.f};
#pragma unroll
        for (int kc = 0; kc < 4; ++kc) {
            const s16x8 wf = *(const s16x8*)(wvb + (size_t)(16 * mt + c16) * 128 + 32 * kc + 8 * g16);
            acc = __builtin_amdgcn_mfma_f32_16x16x32_bf16(wf, xf[kc], acc, 0, 0, 0);
        }
        const float4 bvv = *(const float4*)(bv + 16 * mt + 4 * g16);
#pragma unroll
        for (int r = 0; r < 4; ++r) {
            const int c = 16 * mt + 4 * g16 + r;
            vwp[c * 8] = f2bf(acc[r] + ((const float*)&bvv)[r]);
        }
    }
    // ---- Q, K ----
    f32x4 aq = {0.f, 0.f, 0.f, 0.f}, ak = {0.f, 0.f, 0.f, 0.f};
#pragma unroll
    for (int kc = 0; kc < 4; ++kc) {
        const s16x8 wqf = *(const s16x8*)(wqb + (size_t)c16 * 128 + 32 * kc + 8 * g16);
        const s16x8 wkf = *(const s16x8*)(wkb + (size_t)c16 * 128 + 32 * kc + 8 * g16);
        aq = __builtin_amdgcn_mfma_f32_16x16x32_bf16(xf[kc], wqf, aq, 0, 0, 0);
        ak = __builtin_amdgcn_mfma_f32_16x16x32_bf16(xf[kc], wkf, ak, 0, 0, 0);
    }
    const float bqv = bq[c16], bkv = bk[c16];
#pragma unroll
    for (int r = 0; r < 4; ++r) {
        const int n = n0 + 16 * w + 4 * g16 + r;
        qb[((size_t)b * NTOK + n) * 16 + c16] = f2bf(0.25f * (aq[r] + bqv));
        kb[((size_t)b * NTOK + n) * 16 + c16] = f2bf(ak[r] + bkv);
    }
}

// ---------------- P2: flash attention, 32x32x16 MFMA, XCD-pinned ----------------
// Flat grid 1024 blocks: b = blk & 7 (one batch per XCD), m-tile = blk >> 3 (32 q rows).
// 4 waves: wave w covers j in [w*1024, (w+1)*1024); partials combined via LDS.
// P C->B layout transform done entirely in registers via ds_bpermute (no LDS
// storage, no wave_barrier ordering assumptions, no bank conflicts).
// launch_bounds (256,2): proven no-spill config (VGPR ~112-160).
__global__ __launch_bounds__(256, 2) void flash_kernel(
    const unsigned short* __restrict__ qb, const unsigned short* __restrict__ kb,
    const unsigned short* __restrict__ vt, const float* __restrict__ x,
    const float* __restrict__ gamma, float* __restrict__ out)
{
    __shared__ float smem[4256];  // combine only: ob[128*33] + lb[32]

    const int t = threadIdx.x;
    const int w = t >> 6, lane = t & 63;
    const int m31 = lane & 31, h = lane >> 5;
    const int b  = blockIdx.x & 7;
    const int m0 = (blockIdx.x >> 3) * 32;

    const unsigned short* kbb = kb + ((size_t)b * NTOK + w * 1024) * 16;
    // fragment-major V base for this wave's 16 jt tiles
    const unsigned short* vtb = vt + (size_t)b * (NTOK * 128) + (size_t)w * 16 * 8192 +
                                h * 1024 + m31 * 8;

    // Q B-frag: B[k=ch 8h+e][n=m31]; scale pre-folded into qb.
    const s16x8 qf = *(const s16x8*)(qb + ((size_t)b * NTOK + m0 + m31) * 16 + 8 * h);

    f32x16 O[4];
#pragma unroll
    for (int ct = 0; ct < 4; ++ct)
#pragma unroll
        for (int r = 0; r < 16; ++r) O[ct][r] = 0.f;
    float l_acc = 0.f;

    // K A-frags for jt=0
    s16x8 kf0 = *(const s16x8*)(kbb + (size_t)m31 * 16 + 8 * h);
    s16x8 kf1 = *(const s16x8*)(kbb + (size_t)(32 + m31) * 16 + 8 * h);

    const int xaddr = (lane ^ 32) << 2;   // bpermute byte-address of h-partner

    for (int jt = 0; jt < 16; ++jt) {
        const int j0 = jt * 64;

        // V A-frags, coalesced (two contiguous 512B segments per load)
        s16x8 vf[4][4];
#pragma unroll
        for (int s = 0; s < 4; ++s)
#pragma unroll
            for (int ct = 0; ct < 4; ++ct)
                vf[ct][s] = *(const s16x8*)(vtb + jt * 8192 + s * 2048 + ct * 256);

        // scores: S^T tiles (D[j][m])
        f32x16 sd[2];
#pragma unroll
        for (int r = 0; r < 16; ++r) { sd[0][r] = 0.f; sd[1][r] = 0.f; }
        sd[0] = __builtin_amdgcn_mfma_f32_32x32x16_bf16(kf0, qf, sd[0], 0, 0, 0);
        sd[1] = __builtin_amdgcn_mfma_f32_32x32x16_bf16(kf1, qf, sd[1], 0, 0, 0);

        // prefetch next K frags
        if (jt < 15) {
            kf0 = *(const s16x8*)(kbb + (size_t)(j0 + 64 + m31) * 16 + 8 * h);
            kf1 = *(const s16x8*)(kbb + (size_t)(j0 + 96 + m31) * 16 + 8 * h);
        }

        // softmax without max-subtraction (|s| bounded; exp safe in fp32)
#pragma unroll
        for (int t2 = 0; t2 < 2; ++t2)
#pragma unroll
            for (int r = 0; r < 16; ++r) {
                const float e = __expf(sd[t2][r]);
                sd[t2][r] = e;
                l_acc += e;
            }

        // pack C/D quads to bf16 dword-pairs: pk[t2][q] <- sd[t2][4q..4q+3]
        uint2 pk[2][4];
#pragma unroll
        for (int t2 = 0; t2 < 2; ++t2)
#pragma unroll
            for (int q = 0; q < 4; ++q) {
                pk[t2][q].x = packbf2(sd[t2][4 * q + 0], sd[t2][4 * q + 1]);
                pk[t2][q].y = packbf2(sd[t2][4 * q + 2], sd[t2][4 * q + 3]);
            }

        // register-only C->B transform: exchange with h-partner (lane^32).
        // send pk[t2][2*s1 + (1-h)]; receive partner's pk[t2][2*s1 + h].
        uint2 ex[2][2];
#pragma unroll
        for (int t2 = 0; t2 < 2; ++t2)
#pragma unroll
            for (int s1 = 0; s1 < 2; ++s1) {
                const uint2 snd = h ? pk[t2][2 * s1] : pk[t2][2 * s1 + 1];
                ex[t2][s1].x = (unsigned)__builtin_amdgcn_ds_bpermute(xaddr, (int)snd.x);
                ex[t2][s1].y = (unsigned)__builtin_amdgcn_ds_bpermute(xaddr, (int)snd.y);
            }

        // assemble pf[s]: B[k=8h+e][n=m31] = P^T[j=16s+8h+e][m31]
        // dwords 0,1 from h'=0 source; dwords 2,3 from h'=1 source.
        s16x8 pf[4];
#pragma unroll
        for (int s = 0; s < 4; ++s) {
            const int t2 = s >> 1, s1 = s & 1;
            const uint2 lo = h ? ex[t2][s1] : pk[t2][2 * s1];
            const uint2 hi = h ? pk[t2][2 * s1 + 1] : ex[t2][s1];
            union { s16x8 v; unsigned u[4]; } asm_;
            asm_.u[0] = lo.x; asm_.u[1] = lo.y; asm_.u[2] = hi.x; asm_.u[3] = hi.y;
            pf[s] = asm_.v;
        }

        // PV: O^T[c][m] += V^T * P^T
#pragma unroll
        for (int s = 0; s < 4; ++s)
#pragma unroll
            for (int ct = 0; ct < 4; ++ct)
                O[ct] = __builtin_amdgcn_mfma_f32_32x32x16_bf16(vf[ct][s], pf[s], O[ct], 0, 0, 0);
    }

    // finish this wave's l (two h-halves hold disjoint j subsets)
    l_acc += __shfl_xor(l_acc, 32);

    // ---- combine 4 j-partials via LDS ----
    float* ob = smem;          // [c][m] stride 33
    float* lb = smem + 4224;   // [32]
#pragma unroll 1
    for (int src = 1; src < 4; ++src) {
        __syncthreads();
        if (w == src) {
#pragma unroll
            for (int ct = 0; ct < 4; ++ct)
#pragma unroll
                for (int r = 0; r < 16; ++r) {
                    const int c = 32 * ct + (r & 3) + 8 * (r >> 2) + 4 * h;
                    ob[c * 33 + m31] = O[ct][r];
                }
            if (lane < 32) lb[lane] = l_acc;
        }
        __syncthreads();
        if (w == 0) {
#pragma unroll
            for (int ct = 0; ct < 4; ++ct)
#pragma unroll
                for (int r = 0; r < 16; ++r) {
                    const int c = 32 * ct + (r & 3) + 8 * (r >> 2) + 4 * h;
                    O[ct][r] += ob[c * 33 + m31];
                }
            l_acc += lb[m31];
        }
    }

    if (w == 0) {
        const float linv = 1.f / l_acc;
        const float g = gamma[0];
#pragma unroll
        for (int ct = 0; ct < 4; ++ct)
#pragma unroll
            for (int r = 0; r < 16; ++r) {
                const int c = 32 * ct + (r & 3) + 8 * (r >> 2) + 4 * h;
                const size_t idx = ((size_t)b * 128 + c) * NTOK + m0 + m31;
                out[idx] = fmaf(g, O[ct][r] * linv, x[idx]);
            }
    }
}

extern "C" void kernel_launch(void* const* d_in, const int* in_sizes, int n_in,
                              void* d_out, int out_size, void* d_ws, size_t ws_size,
                              hipStream_t stream)
{
    const float* x     = (const float*)d_in[0];
    const float* Wq    = (const float*)d_in[1];
    const float* bq    = (const float*)d_in[2];
    const float* Wk    = (const float*)d_in[3];
    const float* bk    = (const float*)d_in[4];
    const float* Wv    = (const float*)d_in[5];
    const float* bv    = (const float*)d_in[6];
    const float* gamma = (const float*)d_in[7];
    float* out = (float*)d_out;

    // workspace (bf16 elements)
    unsigned short* qb  = (unsigned short*)d_ws;                 // 8*4096*16
    unsigned short* kb  = qb  + (size_t)NB_ * NTOK * 16;
    unsigned short* vt  = kb  + (size_t)NB_ * NTOK * 16;         // 8*128*4096 (fragment-major)
    unsigned short* wvb = vt  + (size_t)NB_ * 128 * NTOK;        // 128*128
    unsigned short* wqb = wvb + 16384;                           // 16*128
    unsigned short* wkb = wqb + 2048;

    wcvt_kernel<<<80, 256, 0, stream>>>(Wq, Wk, Wv, wvb, wqb, wkb);
    proj_kernel<<<512, 256, 0, stream>>>(x, wvb, wqb, wkb, bq, bk, bv, qb, kb, vt);
    flash_kernel<<<1024, 256, 0, stream>>>(qb, kb, vt, x, gamma, out);
}